// Round 23
// baseline (440.806 us; speedup 1.0000x reference)
//
#include <hip/hip_runtime.h>
#include <hip/hip_bf16.h>

// Problem constants
#define NB 16384      // batch rows
#define DD 512        // IN+OUT
#define NCOLS 4096    // 4*OUT*NCELL

typedef __attribute__((ext_vector_type(8))) short short8;
typedef __attribute__((ext_vector_type(4))) float f32x4;

// Fast-approx activations (R15-proven: output tol 0.0837 >> 1-ulp rcp/exp2 err)
__device__ __forceinline__ float sigmoidf_(float x) {
    float e = __builtin_amdgcn_exp2f(-1.442695041f * x);   // exp(-x)
    return __builtin_amdgcn_rcpf(1.f + e);
}
__device__ __forceinline__ float tanhf_(float x) {
    float e = __builtin_amdgcn_exp2f(-2.885390082f * x);   // exp(-2x)
    return 2.f * __builtin_amdgcn_rcpf(1.f + e) - 1.f;
}

#define GLOAD_LDS16(g, l) __builtin_amdgcn_global_load_lds( \
    (__attribute__((address_space(1))) void*)(g), \
    (__attribute__((address_space(3))) void*)(l), 16, 0, 0)

// ---------------- P1 (fused): feats->bf16 + ctrl gates | W_gates repack to W4 ----
// Also zeroes counts (block 0) — removes the memset dispatch node.
__global__ void k_pre(const float* __restrict__ x, const float* __restrict__ h,
                      const float* __restrict__ Wc, const float* __restrict__ bc,
                      const float* __restrict__ Wg,
                      __hip_bfloat16* __restrict__ featsB, float* __restrict__ gates,
                      __hip_bfloat16* __restrict__ W4, int* __restrict__ counts) {
    int bid = blockIdx.x;
    if (bid == 0 && threadIdx.x < 6) counts[threadIdx.x] = 0;
    if (bid < 4096) {
        int wave = bid * 4 + (threadIdx.x >> 6);  // == row
        int lane = threadIdx.x & 63;
        int row = wave;
        int k0 = lane * 8;
        const float* src = (k0 < 256) ? (x + (size_t)row * 256 + k0)
                                      : (h + (size_t)row * 256 + k0 - 256);
        float4 f0 = ((const float4*)src)[0];
        float4 f1 = ((const float4*)src)[1];
        float fv[8] = {f0.x, f0.y, f0.z, f0.w, f1.x, f1.y, f1.z, f1.w};
        __hip_bfloat16 tmp[8];
#pragma unroll
        for (int j = 0; j < 8; ++j) tmp[j] = __float2bfloat16(fv[j]);
        *reinterpret_cast<short8*>(featsB + (size_t)row * 512 + k0) =
            *reinterpret_cast<short8*>(tmp);
        float acc[4] = {0.f, 0.f, 0.f, 0.f};
#pragma unroll
        for (int j = 0; j < 8; ++j) {
            float4 w = ((const float4*)Wc)[k0 + j];
            acc[0] += fv[j] * w.x; acc[1] += fv[j] * w.y;
            acc[2] += fv[j] * w.z; acc[3] += fv[j] * w.w;
        }
#pragma unroll
        for (int off = 32; off; off >>= 1) {
#pragma unroll
            for (int c = 0; c < 4; ++c) acc[c] += __shfl_xor(acc[c], off);
        }
        if (lane == 0) {
            float l[4];
#pragma unroll
            for (int c = 0; c < 4; ++c) l[c] = acc[c] + bc[c];
            int i1 = 0;
#pragma unroll
            for (int c = 1; c < 4; ++c) if (l[c] > l[i1]) i1 = c;  // ties -> lowest
            int i2 = -1;
#pragma unroll
            for (int c = 0; c < 4; ++c)
                if (c != i1 && (i2 < 0 || l[c] > l[i2])) i2 = c;
            // selection must match numpy: f32 logits, exact expf here (cheap, once)
            float e = __expf(l[i2] - l[i1]);   // <= 1
            float p1 = 1.f / (1.f + e);
            float p2 = e / (1.f + e);
            float g[4] = {0.f, 0.f, 0.f, 0.f};
            g[i1] = p1; g[i2] = p2;
            float4 gv; gv.x = g[0]; gv.y = g[1]; gv.z = g[2]; gv.w = g[3];
            *(float4*)(gates + (size_t)row * 4) = gv;
        }
    } else {
        int c = (bid - 4096) * 256 + threadIdx.x;   // chunk id, 0..262143
        int lane = c & 63;
        int kkg  = (c >> 6) & 15;
        int rowg = (c >> 10) & 7;
        int ob   = (c >> 13) & 7;
        int cell = c >> 16;
        int oi = lane & 15, hi = lane >> 4;
        int gate = rowg & 3, oh = rowg >> 2;
        int col = cell * 1024 + gate * 256 + ob * 32 + oh * 16 + oi;
        int kb = kkg * 32 + hi * 8;
        __hip_bfloat16 tmp[8];
#pragma unroll
        for (int j = 0; j < 8; ++j)
            tmp[j] = __float2bfloat16(Wg[(size_t)(kb + j) * 4096 + col]);
        *reinterpret_cast<short8*>(W4 + (size_t)c * 8) = *reinterpret_cast<short8*>(tmp);
    }
}

// ---------------- P2: bucket rows, TWO-LEVEL aggregation (R18-proven) ------------
__global__ void k_bucket(const float* __restrict__ gates, int* __restrict__ counts,
                         int* __restrict__ rowList) {
    __shared__ int wcnt[4][6];
    __shared__ int wbase[4][6];
    int tid = threadIdx.x;
    int wave = tid >> 6, lane = tid & 63;
    int row = blockIdx.x * 256 + tid;
    float4 g = *(const float4*)(gates + (size_t)row * 4);
    int i1 = 0; float m1 = g.x;
    if (g.y > m1) { m1 = g.y; i1 = 1; }
    if (g.z > m1) { m1 = g.z; i1 = 2; }
    if (g.w > m1) { m1 = g.w; i1 = 3; }
    int i2 = -1; float m2 = -1.f;
    if (i1 != 0)             { m2 = g.x; i2 = 0; }
    if (i1 != 1 && g.y > m2) { m2 = g.y; i2 = 1; }
    if (i1 != 2 && g.z > m2) { m2 = g.z; i2 = 2; }
    if (i1 != 3 && g.w > m2) { m2 = g.w; i2 = 3; }
    int a = min(i1, i2), b = max(i1, i2);
    int pid = (a == 0) ? (b - 1) : (a == 1) ? (1 + b) : 5;
    int pre = 0;
#pragma unroll
    for (int q = 0; q < 6; ++q) {
        unsigned long long m = __ballot(pid == q);   // uniform execution
        if (pid == q) pre = __popcll(m & ((1ull << lane) - 1ull));
        if (lane == 0) wcnt[wave][q] = __popcll(m);
    }
    __syncthreads();
    if (tid < 6) {
        int q = tid;
        int t0 = wcnt[0][q], t1 = wcnt[1][q], t2 = wcnt[2][q], t3 = wcnt[3][q];
        int tot = t0 + t1 + t2 + t3;
        int base = (tot > 0) ? atomicAdd(counts + q, tot) : 0;
        wbase[0][q] = base;
        wbase[1][q] = base + t0;
        wbase[2][q] = base + t0 + t1;
        wbase[3][q] = base + t0 + t1 + t2;
    }
    __syncthreads();
    rowList[pid * 16384 + wbase[wave][pid] + pre] = row;
}

// ---------------- Main: pair-bucketed GEMM, B-in-register + A-LDS-dbuf ----------
// R21 configuration + R22 change: __launch_bounds__(256,6). Natural VGPR usage
// is 72-76 (cap 85 at 6 waves/EU) and LDS 25.6KB allows 6 blocks/CU — the old
// (256,3) bound (leftover from R12's 145-VGPR design) was pinning residency at
// 3 blocks/CU. 6 resident blocks double the TLP that hides each block's
// per-tile vmcnt(0) drain. Spill tripwire: VGPR~85 + FETCH explosion -> revert.
__launch_bounds__(256, 6)
__global__ void k_main(const __hip_bfloat16* __restrict__ featsB,
                       const __hip_bfloat16* __restrict__ W4,
                       const float* __restrict__ cin,
                       const float* __restrict__ gates,
                       const float* __restrict__ bg,
                       const int* __restrict__ counts,
                       const int* __restrict__ rowList,
                       float* __restrict__ out) {
    __shared__ char smem[25600];          // A[2][8192] | cinS 8K | gatesS 1K
    float* oAcc  = (float*)smem;          // [2][64][32] f32 — aliases A bufs only
    float* cinS  = (float*)(smem + 16384);   // [64][32] (hi-swizzled layout)
    float* gatesS = (float*)(smem + 24576);  // [64][4]

    int tid = threadIdx.x;
    int wave = tid >> 6, lane = tid & 63;
    int wc = wave;                        // (ch, ohh) selector
    int hi = lane >> 4, lsw = lane & 7, l15 = lane & 15;

    // R10/R15 XCD-clustered decode: lin%8 = XCD = bq%8
    int lin = blockIdx.x;                 // [0, 2176)
    int r_ = lin & 7;
    int v_ = lin >> 3;                    // [0, 272)
    int ob = v_ & 7;
    int bq = r_ + ((v_ >> 3) << 3);       // [0, 272), bq%8 == r_

    int c0_ = counts[0], c1_ = counts[1], c2_ = counts[2],
        c3_ = counts[3], c4_ = counts[4], c5_ = counts[5];
    int s1 = (c0_ + 63) >> 6;
    int s2 = s1 + ((c1_ + 63) >> 6);
    int s3 = s2 + ((c2_ + 63) >> 6);
    int s4 = s3 + ((c3_ + 63) >> 6);
    int s5 = s4 + ((c4_ + 63) >> 6);
    int total = s5 + ((c5_ + 63) >> 6);
    if (bq >= total) return;
    int p, chunk, cnt, cA, cB;
    if      (bq < s1) { p = 0; chunk = bq;      cnt = c0_; cA = 0; cB = 1; }
    else if (bq < s2) { p = 1; chunk = bq - s1; cnt = c1_; cA = 0; cB = 2; }
    else if (bq < s3) { p = 2; chunk = bq - s2; cnt = c2_; cA = 0; cB = 3; }
    else if (bq < s4) { p = 3; chunk = bq - s3; cnt = c3_; cA = 1; cB = 2; }
    else if (bq < s5) { p = 4; chunk = bq - s4; cnt = c4_; cA = 1; cB = 3; }
    else              { p = 5; chunk = bq - s5; cnt = c5_; cA = 2; cB = 3; }
    int nvalid = min(64, cnt - chunk * 64);
    int rowbase = p * 16384 + chunk * 64;

    int ohh = wc & 1;
    int ch  = wc >> 1;
    int cell = ch ? cB : cA;

    // A gather descriptors (R10-proven): 128-B rows = 8 chunks; swizzle key = row&7
    int e0 = tid,        rA0 = e0 >> 3, gA0 = (e0 & 7) ^ (rA0 & 7);
    int e1 = 256 + tid,  rA1 = e1 >> 3, gA1 = (e1 & 7) ^ (rA1 & 7);
    int grA0 = rowList[rowbase + ((rA0 < nvalid) ? rA0 : 0)];
    int grA1 = rowList[rowbase + ((rA1 < nvalid) ? rA1 : 0)];
    const __hip_bfloat16* sA0 = featsB + (size_t)grA0 * 512 + gA0 * 8;
    const __hip_bfloat16* sA1 = featsB + (size_t)grA1 * 512 + gA1 * 8;
    int dA0 = e0 * 16, dA1 = e1 * 16;

    // B wave base in W4 (R8-proven mapping)
    const __hip_bfloat16* bBw =
        W4 + ((size_t)(cell * 8 + ob) * 128 + ohh * 64) * 512 + lane * 8;

    f32x4 acc[4][4];
#pragma unroll
    for (int m = 0; m < 4; ++m)
#pragma unroll
        for (int n = 0; n < 4; ++n)
            acc[m][n] = (f32x4){0.f, 0.f, 0.f, 0.f};

    short8 br[2][4][2];                   // [buf parity][n][kk] — static after unroll

#define STAGE_A(kt_, buf_) do { \
        GLOAD_LDS16(sA0 + (kt_) * 64, smem + (buf_) * 8192 + dA0); \
        GLOAD_LDS16(sA1 + (kt_) * 64, smem + (buf_) * 8192 + dA1); \
    } while (0)
#define LOAD_B(pb_, kt_) do { \
        _Pragma("unroll") \
        for (int n_ = 0; n_ < 4; ++n_) \
            _Pragma("unroll") \
            for (int kk_ = 0; kk_ < 2; ++kk_) \
                br[pb_][n_][kk_] = *reinterpret_cast<const short8*>( \
                    bBw + n_ * 8192 + ((kt_) * 2 + kk_) * 512); \
    } while (0)

    // prologue: tile 0 + EPILOGUE OPERAND PREFETCH (cin/gates -> LDS).
    // cinS stored hi-swizzled: stored[r][d] = cin[r][d ^ 8*hi(r)], achieved by
    // pre-swizzling the global SOURCE offset (gload_lds dest must stay linear).
    STAGE_A(0, 0);
    {
        int ec0 = tid,       rc0 = ec0 >> 3, qc0 = ec0 & 7;
        int ec1 = 256 + tid, rc1 = ec1 >> 3, qc1 = ec1 & 7;
        int k80 = (rc0 & 12) << 1;        // 8*hi(rc0)
        int k81 = (rc1 & 12) << 1;
        int gr0 = rowList[rowbase + ((rc0 < nvalid) ? rc0 : 0)];
        int gr1 = rowList[rowbase + ((rc1 < nvalid) ? rc1 : 0)];
        GLOAD_LDS16(cin + (size_t)gr0 * 256 + ob * 32 + ((qc0 * 4) ^ k80),
                    (char*)cinS + ec0 * 16);
        GLOAD_LDS16(cin + (size_t)gr1 * 256 + ob * 32 + ((qc1 * 4) ^ k81),
                    (char*)cinS + ec1 * 16);
        if (tid < 64) {
            int gr = rowList[rowbase + ((tid < nvalid) ? tid : 0)];
            GLOAD_LDS16(gates + (size_t)gr * 4, (char*)gatesS + tid * 16);
        }
    }
    LOAD_B(0, 0);
    __syncthreads();                      // drains: A(0), cin, gates in LDS

#pragma unroll
    for (int kt = 0; kt < 8; ++kt) {
        const int buf = kt & 1;
        if (kt < 7) {                     // issue next tile's loads BEFORE compute
            STAGE_A(kt + 1, buf ^ 1);
            LOAD_B(buf ^ 1, kt + 1);
        }
        const char* Ab = smem + buf * 8192;
#pragma unroll
        for (int kk = 0; kk < 2; ++kk) {
            short8 fa[4];
#pragma unroll
            for (int m = 0; m < 4; ++m) {
                int row = m * 16 + l15;
                int chunkc = (kk * 4 + hi) ^ lsw;
                fa[m] = *reinterpret_cast<const short8*>(Ab + row * 128 + chunkc * 16);
            }
#pragma unroll
            for (int m = 0; m < 4; ++m)
#pragma unroll
                for (int n = 0; n < 4; ++n)
                    acc[m][n] = __builtin_amdgcn_mfma_f32_16x16x32_bf16(
                        fa[m], br[buf][n][kk], acc[m][n], 0, 0, 0);
        }
        __syncthreads();  // reads of buf done; vmcnt(0) drain covered by compute
    }
#undef STAGE_A
#undef LOAD_B

    // ---- epilogue: operands in LDS (hi-swizzled), fast-approx activations ----
    int og = ob * 32 + ohh * 16 + l15;    // global o in [0,256)
    float bb0 = bg[cell * 1024 + 0 * 256 + og];
    float bb1 = bg[cell * 1024 + 1 * 256 + og];
    float bb2 = bg[cell * 1024 + 2 * 256 + og];
    float bb3 = bg[cell * 1024 + 3 * 256 + og];

#define LSTM_BODY(STORE_OP) \
    _Pragma("unroll") \
    for (int m = 0; m < 4; ++m) { \
        _Pragma("unroll") \
        for (int reg = 0; reg < 4; ++reg) { \
            int r = m * 16 + hi * 4 + reg; \
            int sw = (ohh * 16 + l15) ^ ((r & 12) << 1);  /* ^ 8*hi(r) */ \
            float gw = gatesS[r * 4 + cell]; \
            float iv = sigmoidf_(acc[m][0][reg] + bb0); \
            float jv = acc[m][1][reg] + bb1; \
            float fv = sigmoidf_(acc[m][2][reg] + bb2); \
            float ov = sigmoidf_(acc[m][3][reg] + bb3); \
            float cv = cinS[r * 32 + sw]; \
            float ncl = fv * cv + iv * tanhf_(jv); \
            float nhl = ov * tanhf_(ncl); \
            oAcc[r * 32 + sw] STORE_OP gw * nhl; \
            oAcc[2048 + r * 32 + sw] STORE_OP gw * ncl; \
        } \
    }

    if (ch == 0) { LSTM_BODY(=) }     // cell-A waves cover all [2][64][32] slots
    __syncthreads();
    if (ch == 1) { LSTM_BODY(+=) }    // cell-B waves accumulate
    __syncthreads();
#undef LSTM_BODY

    {
        int r = tid >> 2, q = tid & 3;
        if (r < nvalid) {
            int k8 = (r & 12) << 1;       // 8*hi(r): bits>=3 -> float4 stays contiguous
            int b0 = r * 32 + ((q * 8) ^ k8);
            int b1 = r * 32 + ((q * 8 + 4) ^ k8);
            int grow = rowList[rowbase + r];
            size_t obase = (size_t)grow * 256 + ob * 32 + q * 8;
            *(float4*)&out[obase]     = *(float4*)&oAcc[b0];
            *(float4*)&out[obase + 4] = *(float4*)&oAcc[b1];
            *(float4*)&out[(size_t)NB * 256 + obase]     = *(float4*)&oAcc[2048 + b0];
            *(float4*)&out[(size_t)NB * 256 + obase + 4] = *(float4*)&oAcc[2048 + b1];
        }
    }
}

extern "C" void kernel_launch(void* const* d_in, const int* in_sizes, int n_in,
                              void* d_out, int out_size, void* d_ws, size_t ws_size,
                              hipStream_t stream) {
    const float* x  = (const float*)d_in[0];
    const float* c  = (const float*)d_in[1];
    const float* h  = (const float*)d_in[2];
    const float* Wg = (const float*)d_in[3];
    const float* bg = (const float*)d_in[4];
    const float* Wc = (const float*)d_in[5];
    const float* bc = (const float*)d_in[6];
    float* out = (float*)d_out;

    const size_t featsB_bytes = (size_t)NB * DD * 2;        // 16.78 MB
    const size_t w4_bytes     = (size_t)NCOLS * DD * 2;     // 4.19 MB
    const size_t gates_bytes  = (size_t)NB * 4 * 4;         // 0.26 MB
    const size_t counts_bytes = 256;
    const size_t rlist_bytes  = (size_t)6 * 16384 * 4;      // 0.39 MB
    if (ws_size < featsB_bytes + w4_bytes + gates_bytes + counts_bytes + rlist_bytes)
        return;

    char* ws = (char*)d_ws;
    __hip_bfloat16* featsB = (__hip_bfloat16*)ws;
    __hip_bfloat16* W4     = (__hip_bfloat16*)(ws + featsB_bytes);
    float*          gatesW = (float*)(ws + featsB_bytes + w4_bytes);
    int*            counts = (int*)(ws + featsB_bytes + w4_bytes + gates_bytes);
    int*            rowLst = (int*)(ws + featsB_bytes + w4_bytes + gates_bytes + counts_bytes);

    k_pre<<<dim3(5120), dim3(256), 0, stream>>>(x, h, Wc, bc, Wg, featsB, gatesW,
                                                W4, counts);
    k_bucket<<<dim3(64), dim3(256), 0, stream>>>(gatesW, counts, rowLst);
    // 2176 = 8 XCD-residues x 34 chunk-groups x 8 obs; blocks with bq>=total exit
    k_main<<<dim3(2176), dim3(256), 0, stream>>>(featsB, W4, c, gatesW, bg,
                                                 counts, rowLst, out);
}

// Round 24
// 87.122 us; speedup vs baseline: 5.0596x; 5.0596x over previous
//
#include <hip/hip_runtime.h>
#include <hip/hip_bf16.h>

// Problem constants
#define NB 16384      // batch rows
#define DD 512        // IN+OUT
#define NCOLS 4096    // 4*OUT*NCELL

typedef __attribute__((ext_vector_type(8))) short short8;
typedef __attribute__((ext_vector_type(4))) float f32x4;

// Fast-approx activations (R15-proven: output tol 0.0837 >> 1-ulp rcp/exp2 err)
__device__ __forceinline__ float sigmoidf_(float x) {
    float e = __builtin_amdgcn_exp2f(-1.442695041f * x);   // exp(-x)
    return __builtin_amdgcn_rcpf(1.f + e);
}
__device__ __forceinline__ float tanhf_(float x) {
    float e = __builtin_amdgcn_exp2f(-2.885390082f * x);   // exp(-2x)
    return 2.f * __builtin_amdgcn_rcpf(1.f + e) - 1.f;
}

#define GLOAD_LDS16(g, l) __builtin_amdgcn_global_load_lds( \
    (__attribute__((address_space(1))) void*)(g), \
    (__attribute__((address_space(3))) void*)(l), 16, 0, 0)

// ---------------- P1 (fused): feats->bf16 + ctrl gates | W_gates repack to W4 ----
// Also zeroes counts (block 0) — removes the memset dispatch node.
__global__ void k_pre(const float* __restrict__ x, const float* __restrict__ h,
                      const float* __restrict__ Wc, const float* __restrict__ bc,
                      const float* __restrict__ Wg,
                      __hip_bfloat16* __restrict__ featsB, float* __restrict__ gates,
                      __hip_bfloat16* __restrict__ W4, int* __restrict__ counts) {
    int bid = blockIdx.x;
    if (bid == 0 && threadIdx.x < 6) counts[threadIdx.x] = 0;
    if (bid < 4096) {
        int wave = bid * 4 + (threadIdx.x >> 6);  // == row
        int lane = threadIdx.x & 63;
        int row = wave;
        int k0 = lane * 8;
        const float* src = (k0 < 256) ? (x + (size_t)row * 256 + k0)
                                      : (h + (size_t)row * 256 + k0 - 256);
        float4 f0 = ((const float4*)src)[0];
        float4 f1 = ((const float4*)src)[1];
        float fv[8] = {f0.x, f0.y, f0.z, f0.w, f1.x, f1.y, f1.z, f1.w};
        __hip_bfloat16 tmp[8];
#pragma unroll
        for (int j = 0; j < 8; ++j) tmp[j] = __float2bfloat16(fv[j]);
        *reinterpret_cast<short8*>(featsB + (size_t)row * 512 + k0) =
            *reinterpret_cast<short8*>(tmp);
        float acc[4] = {0.f, 0.f, 0.f, 0.f};
#pragma unroll
        for (int j = 0; j < 8; ++j) {
            float4 w = ((const float4*)Wc)[k0 + j];
            acc[0] += fv[j] * w.x; acc[1] += fv[j] * w.y;
            acc[2] += fv[j] * w.z; acc[3] += fv[j] * w.w;
        }
#pragma unroll
        for (int off = 32; off; off >>= 1) {
#pragma unroll
            for (int c = 0; c < 4; ++c) acc[c] += __shfl_xor(acc[c], off);
        }
        if (lane == 0) {
            float l[4];
#pragma unroll
            for (int c = 0; c < 4; ++c) l[c] = acc[c] + bc[c];
            int i1 = 0;
#pragma unroll
            for (int c = 1; c < 4; ++c) if (l[c] > l[i1]) i1 = c;  // ties -> lowest
            int i2 = -1;
#pragma unroll
            for (int c = 0; c < 4; ++c)
                if (c != i1 && (i2 < 0 || l[c] > l[i2])) i2 = c;
            // selection must match numpy: f32 logits, exact expf here (cheap, once)
            float e = __expf(l[i2] - l[i1]);   // <= 1
            float p1 = 1.f / (1.f + e);
            float p2 = e / (1.f + e);
            float g[4] = {0.f, 0.f, 0.f, 0.f};
            g[i1] = p1; g[i2] = p2;
            float4 gv; gv.x = g[0]; gv.y = g[1]; gv.z = g[2]; gv.w = g[3];
            *(float4*)(gates + (size_t)row * 4) = gv;
        }
    } else {
        int c = (bid - 4096) * 256 + threadIdx.x;   // chunk id, 0..262143
        int lane = c & 63;
        int kkg  = (c >> 6) & 15;
        int rowg = (c >> 10) & 7;
        int ob   = (c >> 13) & 7;
        int cell = c >> 16;
        int oi = lane & 15, hi = lane >> 4;
        int gate = rowg & 3, oh = rowg >> 2;
        int col = cell * 1024 + gate * 256 + ob * 32 + oh * 16 + oi;
        int kb = kkg * 32 + hi * 8;
        __hip_bfloat16 tmp[8];
#pragma unroll
        for (int j = 0; j < 8; ++j)
            tmp[j] = __float2bfloat16(Wg[(size_t)(kb + j) * 4096 + col]);
        *reinterpret_cast<short8*>(W4 + (size_t)c * 8) = *reinterpret_cast<short8*>(tmp);
    }
}

// ---------------- P2: bucket rows, TWO-LEVEL aggregation (R18-proven) ------------
__global__ void k_bucket(const float* __restrict__ gates, int* __restrict__ counts,
                         int* __restrict__ rowList) {
    __shared__ int wcnt[4][6];
    __shared__ int wbase[4][6];
    int tid = threadIdx.x;
    int wave = tid >> 6, lane = tid & 63;
    int row = blockIdx.x * 256 + tid;
    float4 g = *(const float4*)(gates + (size_t)row * 4);
    int i1 = 0; float m1 = g.x;
    if (g.y > m1) { m1 = g.y; i1 = 1; }
    if (g.z > m1) { m1 = g.z; i1 = 2; }
    if (g.w > m1) { m1 = g.w; i1 = 3; }
    int i2 = -1; float m2 = -1.f;
    if (i1 != 0)             { m2 = g.x; i2 = 0; }
    if (i1 != 1 && g.y > m2) { m2 = g.y; i2 = 1; }
    if (i1 != 2 && g.z > m2) { m2 = g.z; i2 = 2; }
    if (i1 != 3 && g.w > m2) { m2 = g.w; i2 = 3; }
    int a = min(i1, i2), b = max(i1, i2);
    int pid = (a == 0) ? (b - 1) : (a == 1) ? (1 + b) : 5;
    int pre = 0;
#pragma unroll
    for (int q = 0; q < 6; ++q) {
        unsigned long long m = __ballot(pid == q);   // uniform execution
        if (pid == q) pre = __popcll(m & ((1ull << lane) - 1ull));
        if (lane == 0) wcnt[wave][q] = __popcll(m);
    }
    __syncthreads();
    if (tid < 6) {
        int q = tid;
        int t0 = wcnt[0][q], t1 = wcnt[1][q], t2 = wcnt[2][q], t3 = wcnt[3][q];
        int tot = t0 + t1 + t2 + t3;
        int base = (tot > 0) ? atomicAdd(counts + q, tot) : 0;
        wbase[0][q] = base;
        wbase[1][q] = base + t0;
        wbase[2][q] = base + t0 + t1;
        wbase[3][q] = base + t0 + t1 + t2;
    }
    __syncthreads();
    rowList[pid * 16384 + wbase[wave][pid] + pre] = row;
}

// ---------------- Main: pair-bucketed GEMM, B-in-register + A-LDS-dbuf ----------
// R21 configuration with __launch_bounds__(256,4): VGPR cap 128 (natural usage
// 72-76 — no spill; R22's (256,6) cap ~85 spilled to 40 VGPR / 1.15GB scratch).
// bq%8 XCD decode, B wave-private in registers from W4 (1KB coalesced wave
// loads), A via global_load_lds double-buffer, ONE __syncthreads per tile,
// epilogue operands prefetched to LDS (R14), fast activations (R15),
// hi-swizzled epilogue LDS (R21).
__launch_bounds__(256, 4)
__global__ void k_main(const __hip_bfloat16* __restrict__ featsB,
                       const __hip_bfloat16* __restrict__ W4,
                       const float* __restrict__ cin,
                       const float* __restrict__ gates,
                       const float* __restrict__ bg,
                       const int* __restrict__ counts,
                       const int* __restrict__ rowList,
                       float* __restrict__ out) {
    __shared__ char smem[25600];          // A[2][8192] | cinS 8K | gatesS 1K
    float* oAcc  = (float*)smem;          // [2][64][32] f32 — aliases A bufs only
    float* cinS  = (float*)(smem + 16384);   // [64][32] (hi-swizzled layout)
    float* gatesS = (float*)(smem + 24576);  // [64][4]

    int tid = threadIdx.x;
    int wave = tid >> 6, lane = tid & 63;
    int wc = wave;                        // (ch, ohh) selector
    int hi = lane >> 4, lsw = lane & 7, l15 = lane & 15;

    // R10/R15 XCD-clustered decode: lin%8 = XCD = bq%8
    int lin = blockIdx.x;                 // [0, 2176)
    int r_ = lin & 7;
    int v_ = lin >> 3;                    // [0, 272)
    int ob = v_ & 7;
    int bq = r_ + ((v_ >> 3) << 3);       // [0, 272), bq%8 == r_

    int c0_ = counts[0], c1_ = counts[1], c2_ = counts[2],
        c3_ = counts[3], c4_ = counts[4], c5_ = counts[5];
    int s1 = (c0_ + 63) >> 6;
    int s2 = s1 + ((c1_ + 63) >> 6);
    int s3 = s2 + ((c2_ + 63) >> 6);
    int s4 = s3 + ((c3_ + 63) >> 6);
    int s5 = s4 + ((c4_ + 63) >> 6);
    int total = s5 + ((c5_ + 63) >> 6);
    if (bq >= total) return;
    int p, chunk, cnt, cA, cB;
    if      (bq < s1) { p = 0; chunk = bq;      cnt = c0_; cA = 0; cB = 1; }
    else if (bq < s2) { p = 1; chunk = bq - s1; cnt = c1_; cA = 0; cB = 2; }
    else if (bq < s3) { p = 2; chunk = bq - s2; cnt = c2_; cA = 0; cB = 3; }
    else if (bq < s4) { p = 3; chunk = bq - s3; cnt = c3_; cA = 1; cB = 2; }
    else if (bq < s5) { p = 4; chunk = bq - s4; cnt = c4_; cA = 1; cB = 3; }
    else              { p = 5; chunk = bq - s5; cnt = c5_; cA = 2; cB = 3; }
    int nvalid = min(64, cnt - chunk * 64);
    int rowbase = p * 16384 + chunk * 64;

    int ohh = wc & 1;
    int ch  = wc >> 1;
    int cell = ch ? cB : cA;

    // A gather descriptors (R10-proven): 128-B rows = 8 chunks; swizzle key = row&7
    int e0 = tid,        rA0 = e0 >> 3, gA0 = (e0 & 7) ^ (rA0 & 7);
    int e1 = 256 + tid,  rA1 = e1 >> 3, gA1 = (e1 & 7) ^ (rA1 & 7);
    int grA0 = rowList[rowbase + ((rA0 < nvalid) ? rA0 : 0)];
    int grA1 = rowList[rowbase + ((rA1 < nvalid) ? rA1 : 0)];
    const __hip_bfloat16* sA0 = featsB + (size_t)grA0 * 512 + gA0 * 8;
    const __hip_bfloat16* sA1 = featsB + (size_t)grA1 * 512 + gA1 * 8;
    int dA0 = e0 * 16, dA1 = e1 * 16;

    // B wave base in W4 (R8-proven mapping)
    const __hip_bfloat16* bBw =
        W4 + ((size_t)(cell * 8 + ob) * 128 + ohh * 64) * 512 + lane * 8;

    f32x4 acc[4][4];
#pragma unroll
    for (int m = 0; m < 4; ++m)
#pragma unroll
        for (int n = 0; n < 4; ++n)
            acc[m][n] = (f32x4){0.f, 0.f, 0.f, 0.f};

    short8 br[2][4][2];                   // [buf parity][n][kk] — static after unroll

#define STAGE_A(kt_, buf_) do { \
        GLOAD_LDS16(sA0 + (kt_) * 64, smem + (buf_) * 8192 + dA0); \
        GLOAD_LDS16(sA1 + (kt_) * 64, smem + (buf_) * 8192 + dA1); \
    } while (0)
#define LOAD_B(pb_, kt_) do { \
        _Pragma("unroll") \
        for (int n_ = 0; n_ < 4; ++n_) \
            _Pragma("unroll") \
            for (int kk_ = 0; kk_ < 2; ++kk_) \
                br[pb_][n_][kk_] = *reinterpret_cast<const short8*>( \
                    bBw + n_ * 8192 + ((kt_) * 2 + kk_) * 512); \
    } while (0)

    // prologue: tile 0 + EPILOGUE OPERAND PREFETCH (cin/gates -> LDS).
    // cinS stored hi-swizzled: stored[r][d] = cin[r][d ^ 8*hi(r)], achieved by
    // pre-swizzling the global SOURCE offset (gload_lds dest must stay linear).
    STAGE_A(0, 0);
    {
        int ec0 = tid,       rc0 = ec0 >> 3, qc0 = ec0 & 7;
        int ec1 = 256 + tid, rc1 = ec1 >> 3, qc1 = ec1 & 7;
        int k80 = (rc0 & 12) << 1;        // 8*hi(rc0)
        int k81 = (rc1 & 12) << 1;
        int gr0 = rowList[rowbase + ((rc0 < nvalid) ? rc0 : 0)];
        int gr1 = rowList[rowbase + ((rc1 < nvalid) ? rc1 : 0)];
        GLOAD_LDS16(cin + (size_t)gr0 * 256 + ob * 32 + ((qc0 * 4) ^ k80),
                    (char*)cinS + ec0 * 16);
        GLOAD_LDS16(cin + (size_t)gr1 * 256 + ob * 32 + ((qc1 * 4) ^ k81),
                    (char*)cinS + ec1 * 16);
        if (tid < 64) {
            int gr = rowList[rowbase + ((tid < nvalid) ? tid : 0)];
            GLOAD_LDS16(gates + (size_t)gr * 4, (char*)gatesS + tid * 16);
        }
    }
    LOAD_B(0, 0);
    __syncthreads();                      // drains: A(0), cin, gates in LDS

#pragma unroll
    for (int kt = 0; kt < 8; ++kt) {
        const int buf = kt & 1;
        if (kt < 7) {                     // issue next tile's loads BEFORE compute
            STAGE_A(kt + 1, buf ^ 1);
            LOAD_B(buf ^ 1, kt + 1);
        }
        const char* Ab = smem + buf * 8192;
#pragma unroll
        for (int kk = 0; kk < 2; ++kk) {
            short8 fa[4];
#pragma unroll
            for (int m = 0; m < 4; ++m) {
                int row = m * 16 + l15;
                int chunkc = (kk * 4 + hi) ^ lsw;
                fa[m] = *reinterpret_cast<const short8*>(Ab + row * 128 + chunkc * 16);
            }
#pragma unroll
            for (int m = 0; m < 4; ++m)
#pragma unroll
                for (int n = 0; n < 4; ++n)
                    acc[m][n] = __builtin_amdgcn_mfma_f32_16x16x32_bf16(
                        fa[m], br[buf][n][kk], acc[m][n], 0, 0, 0);
        }
        __syncthreads();  // reads of buf done; vmcnt(0) drain covered by compute
    }
#undef STAGE_A
#undef LOAD_B

    // ---- epilogue: operands in LDS (hi-swizzled), fast-approx activations ----
    int og = ob * 32 + ohh * 16 + l15;    // global o in [0,256)
    float bb0 = bg[cell * 1024 + 0 * 256 + og];
    float bb1 = bg[cell * 1024 + 1 * 256 + og];
    float bb2 = bg[cell * 1024 + 2 * 256 + og];
    float bb3 = bg[cell * 1024 + 3 * 256 + og];

#define LSTM_BODY(STORE_OP) \
    _Pragma("unroll") \
    for (int m = 0; m < 4; ++m) { \
        _Pragma("unroll") \
        for (int reg = 0; reg < 4; ++reg) { \
            int r = m * 16 + hi * 4 + reg; \
            int sw = (ohh * 16 + l15) ^ ((r & 12) << 1);  /* ^ 8*hi(r) */ \
            float gw = gatesS[r * 4 + cell]; \
            float iv = sigmoidf_(acc[m][0][reg] + bb0); \
            float jv = acc[m][1][reg] + bb1; \
            float fv = sigmoidf_(acc[m][2][reg] + bb2); \
            float ov = sigmoidf_(acc[m][3][reg] + bb3); \
            float cv = cinS[r * 32 + sw]; \
            float ncl = fv * cv + iv * tanhf_(jv); \
            float nhl = ov * tanhf_(ncl); \
            oAcc[r * 32 + sw] STORE_OP gw * nhl; \
            oAcc[2048 + r * 32 + sw] STORE_OP gw * ncl; \
        } \
    }

    if (ch == 0) { LSTM_BODY(=) }     // cell-A waves cover all [2][64][32] slots
    __syncthreads();
    if (ch == 1) { LSTM_BODY(+=) }    // cell-B waves accumulate
    __syncthreads();
#undef LSTM_BODY

    {
        int r = tid >> 2, q = tid & 3;
        if (r < nvalid) {
            int k8 = (r & 12) << 1;       // 8*hi(r): bits>=3 -> float4 stays contiguous
            int b0 = r * 32 + ((q * 8) ^ k8);
            int b1 = r * 32 + ((q * 8 + 4) ^ k8);
            int grow = rowList[rowbase + r];
            size_t obase = (size_t)grow * 256 + ob * 32 + q * 8;
            *(float4*)&out[obase]     = *(float4*)&oAcc[b0];
            *(float4*)&out[obase + 4] = *(float4*)&oAcc[b1];
            *(float4*)&out[(size_t)NB * 256 + obase]     = *(float4*)&oAcc[2048 + b0];
            *(float4*)&out[(size_t)NB * 256 + obase + 4] = *(float4*)&oAcc[2048 + b1];
        }
    }
}

extern "C" void kernel_launch(void* const* d_in, const int* in_sizes, int n_in,
                              void* d_out, int out_size, void* d_ws, size_t ws_size,
                              hipStream_t stream) {
    const float* x  = (const float*)d_in[0];
    const float* c  = (const float*)d_in[1];
    const float* h  = (const float*)d_in[2];
    const float* Wg = (const float*)d_in[3];
    const float* bg = (const float*)d_in[4];
    const float* Wc = (const float*)d_in[5];
    const float* bc = (const float*)d_in[6];
    float* out = (float*)d_out;

    const size_t featsB_bytes = (size_t)NB * DD * 2;        // 16.78 MB
    const size_t w4_bytes     = (size_t)NCOLS * DD * 2;     // 4.19 MB
    const size_t gates_bytes  = (size_t)NB * 4 * 4;         // 0.26 MB
    const size_t counts_bytes = 256;
    const size_t rlist_bytes  = (size_t)6 * 16384 * 4;      // 0.39 MB
    if (ws_size < featsB_bytes + w4_bytes + gates_bytes + counts_bytes + rlist_bytes)
        return;

    char* ws = (char*)d_ws;
    __hip_bfloat16* featsB = (__hip_bfloat16*)ws;
    __hip_bfloat16* W4     = (__hip_bfloat16*)(ws + featsB_bytes);
    float*          gatesW = (float*)(ws + featsB_bytes + w4_bytes);
    int*            counts = (int*)(ws + featsB_bytes + w4_bytes + gates_bytes);
    int*            rowLst = (int*)(ws + featsB_bytes + w4_bytes + gates_bytes + counts_bytes);

    k_pre<<<dim3(5120), dim3(256), 0, stream>>>(x, h, Wc, bc, Wg, featsB, gatesW,
                                                W4, counts);
    k_bucket<<<dim3(64), dim3(256), 0, stream>>>(gatesW, counts, rowLst);
    // 2176 = 8 XCD-residues x 34 chunk-groups x 8 obs; blocks with bq>=total exit
    k_main<<<dim3(2176), dim3(256), 0, stream>>>(featsB, W4, c, gatesW, bg,
                                                 counts, rowLst, out);
}

// Round 25
// 81.323 us; speedup vs baseline: 5.4205x; 1.0713x over previous
//
#include <hip/hip_runtime.h>
#include <hip/hip_bf16.h>

// Problem constants
#define NB 16384      // batch rows
#define DD 512        // IN+OUT
#define NCOLS 4096    // 4*OUT*NCELL

typedef __attribute__((ext_vector_type(8))) short short8;
typedef __attribute__((ext_vector_type(4))) float f32x4;

// Fast-approx activations (R15-proven: output tol 0.0837 >> 1-ulp rcp/exp2 err)
__device__ __forceinline__ float sigmoidf_(float x) {
    float e = __builtin_amdgcn_exp2f(-1.442695041f * x);   // exp(-x)
    return __builtin_amdgcn_rcpf(1.f + e);
}
__device__ __forceinline__ float tanhf_(float x) {
    float e = __builtin_amdgcn_exp2f(-2.885390082f * x);   // exp(-2x)
    return 2.f * __builtin_amdgcn_rcpf(1.f + e) - 1.f;
}

#define GLOAD_LDS16(g, l) __builtin_amdgcn_global_load_lds( \
    (__attribute__((address_space(1))) void*)(g), \
    (__attribute__((address_space(3))) void*)(l), 16, 0, 0)

// ---------------- P1 (fused): feats->bf16 + ctrl gates | W_gates repack to W4 ----
// Also zeroes counts (block 0) — removes the memset dispatch node.
__global__ void k_pre(const float* __restrict__ x, const float* __restrict__ h,
                      const float* __restrict__ Wc, const float* __restrict__ bc,
                      const float* __restrict__ Wg,
                      __hip_bfloat16* __restrict__ featsB, float* __restrict__ gates,
                      __hip_bfloat16* __restrict__ W4, int* __restrict__ counts) {
    int bid = blockIdx.x;
    if (bid == 0 && threadIdx.x < 6) counts[threadIdx.x] = 0;
    if (bid < 4096) {
        int wave = bid * 4 + (threadIdx.x >> 6);  // == row
        int lane = threadIdx.x & 63;
        int row = wave;
        int k0 = lane * 8;
        const float* src = (k0 < 256) ? (x + (size_t)row * 256 + k0)
                                      : (h + (size_t)row * 256 + k0 - 256);
        float4 f0 = ((const float4*)src)[0];
        float4 f1 = ((const float4*)src)[1];
        float fv[8] = {f0.x, f0.y, f0.z, f0.w, f1.x, f1.y, f1.z, f1.w};
        __hip_bfloat16 tmp[8];
#pragma unroll
        for (int j = 0; j < 8; ++j) tmp[j] = __float2bfloat16(fv[j]);
        *reinterpret_cast<short8*>(featsB + (size_t)row * 512 + k0) =
            *reinterpret_cast<short8*>(tmp);
        float acc[4] = {0.f, 0.f, 0.f, 0.f};
#pragma unroll
        for (int j = 0; j < 8; ++j) {
            float4 w = ((const float4*)Wc)[k0 + j];
            acc[0] += fv[j] * w.x; acc[1] += fv[j] * w.y;
            acc[2] += fv[j] * w.z; acc[3] += fv[j] * w.w;
        }
#pragma unroll
        for (int off = 32; off; off >>= 1) {
#pragma unroll
            for (int c = 0; c < 4; ++c) acc[c] += __shfl_xor(acc[c], off);
        }
        if (lane == 0) {
            float l[4];
#pragma unroll
            for (int c = 0; c < 4; ++c) l[c] = acc[c] + bc[c];
            int i1 = 0;
#pragma unroll
            for (int c = 1; c < 4; ++c) if (l[c] > l[i1]) i1 = c;  // ties -> lowest
            int i2 = -1;
#pragma unroll
            for (int c = 0; c < 4; ++c)
                if (c != i1 && (i2 < 0 || l[c] > l[i2])) i2 = c;
            // selection must match numpy: f32 logits, exact expf here (cheap, once)
            float e = __expf(l[i2] - l[i1]);   // <= 1
            float p1 = 1.f / (1.f + e);
            float p2 = e / (1.f + e);
            float g[4] = {0.f, 0.f, 0.f, 0.f};
            g[i1] = p1; g[i2] = p2;
            float4 gv; gv.x = g[0]; gv.y = g[1]; gv.z = g[2]; gv.w = g[3];
            *(float4*)(gates + (size_t)row * 4) = gv;
        }
    } else {
        int c = (bid - 4096) * 256 + threadIdx.x;   // chunk id, 0..262143
        int lane = c & 63;
        int kkg  = (c >> 6) & 15;
        int rowg = (c >> 10) & 7;
        int ob   = (c >> 13) & 7;
        int cell = c >> 16;
        int oi = lane & 15, hi = lane >> 4;
        int gate = rowg & 3, oh = rowg >> 2;
        int col = cell * 1024 + gate * 256 + ob * 32 + oh * 16 + oi;
        int kb = kkg * 32 + hi * 8;
        __hip_bfloat16 tmp[8];
#pragma unroll
        for (int j = 0; j < 8; ++j)
            tmp[j] = __float2bfloat16(Wg[(size_t)(kb + j) * 4096 + col]);
        *reinterpret_cast<short8*>(W4 + (size_t)c * 8) = *reinterpret_cast<short8*>(tmp);
    }
}

// ---------------- P2: bucket rows, TWO-LEVEL aggregation (R18-proven) ------------
__global__ void k_bucket(const float* __restrict__ gates, int* __restrict__ counts,
                         int* __restrict__ rowList) {
    __shared__ int wcnt[4][6];
    __shared__ int wbase[4][6];
    int tid = threadIdx.x;
    int wave = tid >> 6, lane = tid & 63;
    int row = blockIdx.x * 256 + tid;
    float4 g = *(const float4*)(gates + (size_t)row * 4);
    int i1 = 0; float m1 = g.x;
    if (g.y > m1) { m1 = g.y; i1 = 1; }
    if (g.z > m1) { m1 = g.z; i1 = 2; }
    if (g.w > m1) { m1 = g.w; i1 = 3; }
    int i2 = -1; float m2 = -1.f;
    if (i1 != 0)             { m2 = g.x; i2 = 0; }
    if (i1 != 1 && g.y > m2) { m2 = g.y; i2 = 1; }
    if (i1 != 2 && g.z > m2) { m2 = g.z; i2 = 2; }
    if (i1 != 3 && g.w > m2) { m2 = g.w; i2 = 3; }
    int a = min(i1, i2), b = max(i1, i2);
    int pid = (a == 0) ? (b - 1) : (a == 1) ? (1 + b) : 5;
    int pre = 0;
#pragma unroll
    for (int q = 0; q < 6; ++q) {
        unsigned long long m = __ballot(pid == q);   // uniform execution
        if (pid == q) pre = __popcll(m & ((1ull << lane) - 1ull));
        if (lane == 0) wcnt[wave][q] = __popcll(m);
    }
    __syncthreads();
    if (tid < 6) {
        int q = tid;
        int t0 = wcnt[0][q], t1 = wcnt[1][q], t2 = wcnt[2][q], t3 = wcnt[3][q];
        int tot = t0 + t1 + t2 + t3;
        int base = (tot > 0) ? atomicAdd(counts + q, tot) : 0;
        wbase[0][q] = base;
        wbase[1][q] = base + t0;
        wbase[2][q] = base + t0 + t1;
        wbase[3][q] = base + t0 + t1 + t2;
    }
    __syncthreads();
    rowList[pid * 16384 + wbase[wave][pid] + pre] = row;
}

// ---------------- Main: pair-bucketed GEMM, B-in-register + A-LDS-dbuf ----------
// CHAMPION (R21, twice-validated 82.1-82.8 µs total): __launch_bounds__(256,3)
// — the allocator needs the full 72-76 VGPR + headroom; (256,4) spilled mildly
// (64 VGPR, +30MB scratch, 87 µs) and (256,6) catastrophically (40 VGPR, 441 µs).
// bq%8 XCD decode, B wave-private in registers from W4 (1KB coalesced wave
// loads), A via global_load_lds double-buffer, ONE __syncthreads per tile,
// epilogue operands prefetched to LDS (R14), fast activations (R15),
// hi-swizzled epilogue LDS (R21).
__launch_bounds__(256, 3)
__global__ void k_main(const __hip_bfloat16* __restrict__ featsB,
                       const __hip_bfloat16* __restrict__ W4,
                       const float* __restrict__ cin,
                       const float* __restrict__ gates,
                       const float* __restrict__ bg,
                       const int* __restrict__ counts,
                       const int* __restrict__ rowList,
                       float* __restrict__ out) {
    __shared__ char smem[25600];          // A[2][8192] | cinS 8K | gatesS 1K
    float* oAcc  = (float*)smem;          // [2][64][32] f32 — aliases A bufs only
    float* cinS  = (float*)(smem + 16384);   // [64][32] (hi-swizzled layout)
    float* gatesS = (float*)(smem + 24576);  // [64][4]

    int tid = threadIdx.x;
    int wave = tid >> 6, lane = tid & 63;
    int wc = wave;                        // (ch, ohh) selector
    int hi = lane >> 4, lsw = lane & 7, l15 = lane & 15;

    // R10/R15 XCD-clustered decode: lin%8 = XCD = bq%8
    int lin = blockIdx.x;                 // [0, 2176)
    int r_ = lin & 7;
    int v_ = lin >> 3;                    // [0, 272)
    int ob = v_ & 7;
    int bq = r_ + ((v_ >> 3) << 3);       // [0, 272), bq%8 == r_

    int c0_ = counts[0], c1_ = counts[1], c2_ = counts[2],
        c3_ = counts[3], c4_ = counts[4], c5_ = counts[5];
    int s1 = (c0_ + 63) >> 6;
    int s2 = s1 + ((c1_ + 63) >> 6);
    int s3 = s2 + ((c2_ + 63) >> 6);
    int s4 = s3 + ((c3_ + 63) >> 6);
    int s5 = s4 + ((c4_ + 63) >> 6);
    int total = s5 + ((c5_ + 63) >> 6);
    if (bq >= total) return;
    int p, chunk, cnt, cA, cB;
    if      (bq < s1) { p = 0; chunk = bq;      cnt = c0_; cA = 0; cB = 1; }
    else if (bq < s2) { p = 1; chunk = bq - s1; cnt = c1_; cA = 0; cB = 2; }
    else if (bq < s3) { p = 2; chunk = bq - s2; cnt = c2_; cA = 0; cB = 3; }
    else if (bq < s4) { p = 3; chunk = bq - s3; cnt = c3_; cA = 1; cB = 2; }
    else if (bq < s5) { p = 4; chunk = bq - s4; cnt = c4_; cA = 1; cB = 3; }
    else              { p = 5; chunk = bq - s5; cnt = c5_; cA = 2; cB = 3; }
    int nvalid = min(64, cnt - chunk * 64);
    int rowbase = p * 16384 + chunk * 64;

    int ohh = wc & 1;
    int ch  = wc >> 1;
    int cell = ch ? cB : cA;

    // A gather descriptors (R10-proven): 128-B rows = 8 chunks; swizzle key = row&7
    int e0 = tid,        rA0 = e0 >> 3, gA0 = (e0 & 7) ^ (rA0 & 7);
    int e1 = 256 + tid,  rA1 = e1 >> 3, gA1 = (e1 & 7) ^ (rA1 & 7);
    int grA0 = rowList[rowbase + ((rA0 < nvalid) ? rA0 : 0)];
    int grA1 = rowList[rowbase + ((rA1 < nvalid) ? rA1 : 0)];
    const __hip_bfloat16* sA0 = featsB + (size_t)grA0 * 512 + gA0 * 8;
    const __hip_bfloat16* sA1 = featsB + (size_t)grA1 * 512 + gA1 * 8;
    int dA0 = e0 * 16, dA1 = e1 * 16;

    // B wave base in W4 (R8-proven mapping)
    const __hip_bfloat16* bBw =
        W4 + ((size_t)(cell * 8 + ob) * 128 + ohh * 64) * 512 + lane * 8;

    f32x4 acc[4][4];
#pragma unroll
    for (int m = 0; m < 4; ++m)
#pragma unroll
        for (int n = 0; n < 4; ++n)
            acc[m][n] = (f32x4){0.f, 0.f, 0.f, 0.f};

    short8 br[2][4][2];                   // [buf parity][n][kk] — static after unroll

#define STAGE_A(kt_, buf_) do { \
        GLOAD_LDS16(sA0 + (kt_) * 64, smem + (buf_) * 8192 + dA0); \
        GLOAD_LDS16(sA1 + (kt_) * 64, smem + (buf_) * 8192 + dA1); \
    } while (0)
#define LOAD_B(pb_, kt_) do { \
        _Pragma("unroll") \
        for (int n_ = 0; n_ < 4; ++n_) \
            _Pragma("unroll") \
            for (int kk_ = 0; kk_ < 2; ++kk_) \
                br[pb_][n_][kk_] = *reinterpret_cast<const short8*>( \
                    bBw + n_ * 8192 + ((kt_) * 2 + kk_) * 512); \
    } while (0)

    // prologue: tile 0 + EPILOGUE OPERAND PREFETCH (cin/gates -> LDS).
    // cinS stored hi-swizzled: stored[r][d] = cin[r][d ^ 8*hi(r)], achieved by
    // pre-swizzling the global SOURCE offset (gload_lds dest must stay linear).
    STAGE_A(0, 0);
    {
        int ec0 = tid,       rc0 = ec0 >> 3, qc0 = ec0 & 7;
        int ec1 = 256 + tid, rc1 = ec1 >> 3, qc1 = ec1 & 7;
        int k80 = (rc0 & 12) << 1;        // 8*hi(rc0)
        int k81 = (rc1 & 12) << 1;
        int gr0 = rowList[rowbase + ((rc0 < nvalid) ? rc0 : 0)];
        int gr1 = rowList[rowbase + ((rc1 < nvalid) ? rc1 : 0)];
        GLOAD_LDS16(cin + (size_t)gr0 * 256 + ob * 32 + ((qc0 * 4) ^ k80),
                    (char*)cinS + ec0 * 16);
        GLOAD_LDS16(cin + (size_t)gr1 * 256 + ob * 32 + ((qc1 * 4) ^ k81),
                    (char*)cinS + ec1 * 16);
        if (tid < 64) {
            int gr = rowList[rowbase + ((tid < nvalid) ? tid : 0)];
            GLOAD_LDS16(gates + (size_t)gr * 4, (char*)gatesS + tid * 16);
        }
    }
    LOAD_B(0, 0);
    __syncthreads();                      // drains: A(0), cin, gates in LDS

#pragma unroll
    for (int kt = 0; kt < 8; ++kt) {
        const int buf = kt & 1;
        if (kt < 7) {                     // issue next tile's loads BEFORE compute
            STAGE_A(kt + 1, buf ^ 1);
            LOAD_B(buf ^ 1, kt + 1);
        }
        const char* Ab = smem + buf * 8192;
#pragma unroll
        for (int kk = 0; kk < 2; ++kk) {
            short8 fa[4];
#pragma unroll
            for (int m = 0; m < 4; ++m) {
                int row = m * 16 + l15;
                int chunkc = (kk * 4 + hi) ^ lsw;
                fa[m] = *reinterpret_cast<const short8*>(Ab + row * 128 + chunkc * 16);
            }
#pragma unroll
            for (int m = 0; m < 4; ++m)
#pragma unroll
                for (int n = 0; n < 4; ++n)
                    acc[m][n] = __builtin_amdgcn_mfma_f32_16x16x32_bf16(
                        fa[m], br[buf][n][kk], acc[m][n], 0, 0, 0);
        }
        __syncthreads();  // reads of buf done; vmcnt(0) drain covered by compute
    }
#undef STAGE_A
#undef LOAD_B

    // ---- epilogue: operands in LDS (hi-swizzled), fast-approx activations ----
    int og = ob * 32 + ohh * 16 + l15;    // global o in [0,256)
    float bb0 = bg[cell * 1024 + 0 * 256 + og];
    float bb1 = bg[cell * 1024 + 1 * 256 + og];
    float bb2 = bg[cell * 1024 + 2 * 256 + og];
    float bb3 = bg[cell * 1024 + 3 * 256 + og];

#define LSTM_BODY(STORE_OP) \
    _Pragma("unroll") \
    for (int m = 0; m < 4; ++m) { \
        _Pragma("unroll") \
        for (int reg = 0; reg < 4; ++reg) { \
            int r = m * 16 + hi * 4 + reg; \
            int sw = (ohh * 16 + l15) ^ ((r & 12) << 1);  /* ^ 8*hi(r) */ \
            float gw = gatesS[r * 4 + cell]; \
            float iv = sigmoidf_(acc[m][0][reg] + bb0); \
            float jv = acc[m][1][reg] + bb1; \
            float fv = sigmoidf_(acc[m][2][reg] + bb2); \
            float ov = sigmoidf_(acc[m][3][reg] + bb3); \
            float cv = cinS[r * 32 + sw]; \
            float ncl = fv * cv + iv * tanhf_(jv); \
            float nhl = ov * tanhf_(ncl); \
            oAcc[r * 32 + sw] STORE_OP gw * nhl; \
            oAcc[2048 + r * 32 + sw] STORE_OP gw * ncl; \
        } \
    }

    if (ch == 0) { LSTM_BODY(=) }     // cell-A waves cover all [2][64][32] slots
    __syncthreads();
    if (ch == 1) { LSTM_BODY(+=) }    // cell-B waves accumulate
    __syncthreads();
#undef LSTM_BODY

    {
        int r = tid >> 2, q = tid & 3;
        if (r < nvalid) {
            int k8 = (r & 12) << 1;       // 8*hi(r): bits>=3 -> float4 stays contiguous
            int b0 = r * 32 + ((q * 8) ^ k8);
            int b1 = r * 32 + ((q * 8 + 4) ^ k8);
            int grow = rowList[rowbase + r];
            size_t obase = (size_t)grow * 256 + ob * 32 + q * 8;
            *(float4*)&out[obase]     = *(float4*)&oAcc[b0];
            *(float4*)&out[obase + 4] = *(float4*)&oAcc[b1];
            *(float4*)&out[(size_t)NB * 256 + obase]     = *(float4*)&oAcc[2048 + b0];
            *(float4*)&out[(size_t)NB * 256 + obase + 4] = *(float4*)&oAcc[2048 + b1];
        }
    }
}

extern "C" void kernel_launch(void* const* d_in, const int* in_sizes, int n_in,
                              void* d_out, int out_size, void* d_ws, size_t ws_size,
                              hipStream_t stream) {
    const float* x  = (const float*)d_in[0];
    const float* c  = (const float*)d_in[1];
    const float* h  = (const float*)d_in[2];
    const float* Wg = (const float*)d_in[3];
    const float* bg = (const float*)d_in[4];
    const float* Wc = (const float*)d_in[5];
    const float* bc = (const float*)d_in[6];
    float* out = (float*)d_out;

    const size_t featsB_bytes = (size_t)NB * DD * 2;        // 16.78 MB
    const size_t w4_bytes     = (size_t)NCOLS * DD * 2;     // 4.19 MB
    const size_t gates_bytes  = (size_t)NB * 4 * 4;         // 0.26 MB
    const size_t counts_bytes = 256;
    const size_t rlist_bytes  = (size_t)6 * 16384 * 4;      // 0.39 MB
    if (ws_size < featsB_bytes + w4_bytes + gates_bytes + counts_bytes + rlist_bytes)
        return;

    char* ws = (char*)d_ws;
    __hip_bfloat16* featsB = (__hip_bfloat16*)ws;
    __hip_bfloat16* W4     = (__hip_bfloat16*)(ws + featsB_bytes);
    float*          gatesW = (float*)(ws + featsB_bytes + w4_bytes);
    int*            counts = (int*)(ws + featsB_bytes + w4_bytes + gates_bytes);
    int*            rowLst = (int*)(ws + featsB_bytes + w4_bytes + gates_bytes + counts_bytes);

    k_pre<<<dim3(5120), dim3(256), 0, stream>>>(x, h, Wc, bc, Wg, featsB, gatesW,
                                                W4, counts);
    k_bucket<<<dim3(64), dim3(256), 0, stream>>>(gatesW, counts, rowLst);
    // 2176 = 8 XCD-residues x 34 chunk-groups x 8 obs; blocks with bq>=total exit
    k_main<<<dim3(2176), dim3(256), 0, stream>>>(featsB, W4, c, gatesW, bg,
                                                 counts, rowLst, out);
}